// Round 1
// baseline (31.547 us; speedup 1.0000x reference)
//
#include <hip/hip_runtime.h>
#include <math.h>

// Problem constants (match reference)
constexpr int NB     = 8192;        // batch rows
constexpr int TO     = 720;         // forecast/target length
constexpr int TI     = 1440;        // insample length
constexpr int FRQ    = 24;          // seasonal lag
constexpr int NV4    = TO / 4;      // 180 float4 per row
constexpr int NDIFF  = TI - FRQ;    // 1416 diffs per row
constexpr int NDIFF4 = NDIFF / 4;   // 354 float4 diffs per row

__device__ __forceinline__ float wredSum(float v) {
#pragma unroll
    for (int o = 32; o > 0; o >>= 1) v += __shfl_xor(v, o, 64);
    return v;
}
__device__ __forceinline__ float wredMax(float v) {
#pragma unroll
    for (int o = 32; o > 0; o >>= 1) v = fmaxf(v, __shfl_xor(v, o, 64));
    return v;
}

// 256-thread (4-wave) block reduction; broadcasts result to all threads.
__device__ __forceinline__ float bredSum(float v, float* lds) {
    const int lane = threadIdx.x & 63, w = threadIdx.x >> 6;
    v = wredSum(v);
    __syncthreads();                 // protect lds reuse across calls
    if (lane == 0) lds[w] = v;
    __syncthreads();
    return (lds[0] + lds[1]) + (lds[2] + lds[3]);
}
__device__ __forceinline__ float bredMax(float v, float* lds) {
    const int lane = threadIdx.x & 63, w = threadIdx.x >> 6;
    v = wredMax(v);
    __syncthreads();
    if (lane == 0) lds[w] = v;
    __syncthreads();
    return fmaxf(fmaxf(lds[0], lds[1]), fmaxf(lds[2], lds[3]));
}

// One block per row. Each thread t < 180 owns elements [4t, 4t+4) of the
// 720-wide row (dyy stays in registers -> forecast/target/mask read once).
__global__ __launch_bounds__(256) void tildeq_row_kernel(
    const float* __restrict__ insample,
    const float* __restrict__ forecast,
    const float* __restrict__ target,
    const float* __restrict__ mask,
    float* __restrict__ ws)
{
    __shared__ float lds[4];
    const int b = blockIdx.x;
    const int t = threadIdx.x;

    const float4* f4 = (const float4*)(forecast + (size_t)b * TO);
    const float4* g4 = (const float4*)(target   + (size_t)b * TO);
    const float4* m4 = (const float4*)(mask     + (size_t)b * TO);

    float dyy[4] = {0.f, 0.f, 0.f, 0.f};
    float smape_p = 0.f, mase_p = 0.f;
    float lmax = -INFINITY;
    const bool active = (t < NV4);

    if (active) {
        float4 fa = f4[t], ga = g4[t], ma = m4[t];
        float fv[4] = {fa.x, fa.y, fa.z, fa.w};
        float gv[4] = {ga.x, ga.y, ga.z, ga.w};
        float mv[4] = {ma.x, ma.y, ma.z, ma.w};
#pragma unroll
        for (int j = 0; j < 4; ++j) {
            float d  = gv[j] - fv[j];
            float ad = fabsf(d);
            dyy[j] = d * mv[j];                       // (target-forecast)*mask
            lmax   = fmaxf(lmax, dyy[j]);
            mase_p += ad * mv[j];                     // |t-f| * mask
            float den = fabsf(fv[j]) + fabsf(gv[j]);  // detached denom
            float r = (den > 0.f) ? (ad / den) : 0.f; // divide_no_nan
            if (!(r < INFINITY)) r = 0.f;             // kill +inf / NaN
            smape_p += r * mv[j];
        }
    }

    // masep: sum |insample[i+24] - insample[i]|, i in [0,1416). Both the
    // base and +24 (= +6 float4) addresses are 16B-aligned; the overlap
    // re-read hits L1.
    const float4* i4 = (const float4*)(insample + (size_t)b * TI);
    float masep_p = 0.f;
    for (int idx = t; idx < NDIFF4; idx += 256) {
        float4 a = i4[idx];
        float4 c = i4[idx + FRQ / 4];
        masep_p += fabsf(c.x - a.x) + fabsf(c.y - a.y)
                 + fabsf(c.z - a.z) + fabsf(c.w - a.w);
    }

    // Softmax over the register-resident dyy.
    const float rmax = bredMax(lmax, lds);
    float pexp[4];
    float sume_p = 0.f;
    if (active) {
#pragma unroll
        for (int j = 0; j < 4; ++j) { pexp[j] = __expf(dyy[j] - rmax); sume_p += pexp[j]; }
    }
    const float sume  = bredSum(sume_p,  lds);
    const float smape = bredSum(smape_p, lds);
    const float mase  = bredSum(mase_p,  lds);
    const float msum  = bredSum(masep_p, lds);

    const float inv_sume = 1.0f / sume;
    float eq_p = 0.f;
    if (active) {
#pragma unroll
        for (int j = 0; j < 4; ++j)
            eq_p += fabsf(1.0f / (float)TO - pexp[j] * inv_sume);
    }
    const float eqsum = bredSum(eq_p, lds);

    if (t == 0) {
        float masep = msum / (float)NDIFF;
        float invm  = (masep == 0.f) ? 0.f : (1.0f / masep);  // divide_no_nan
        if (!(invm < INFINITY)) invm = 0.f;
        float contrib =
            (0.99f * (float)TO / (4.0f * (float)NB)) * eqsum            // mean(loss_TILDEQ)/4
          + (200.0f / ((float)NB * (float)TO)) * smape                  // 200*smape
          + (1.0f  / ((float)NB * (float)TO)) * mase * invm;            // MASE term
        ws[b] = contrib;
    }
}

// Deterministic final reduction of the 8192 per-row contributions.
__global__ __launch_bounds__(256) void tildeq_finalize_kernel(
    const float* __restrict__ ws, float* __restrict__ out)
{
    __shared__ float lds[4];
    const float4* w4 = (const float4*)ws;
    float s = 0.f;
#pragma unroll
    for (int i = threadIdx.x; i < NB / 4; i += 256) {
        float4 v = w4[i];
        s += (v.x + v.y) + (v.z + v.w);
    }
    s = bredSum(s, lds);
    if (threadIdx.x == 0) out[0] = s;
}

extern "C" void kernel_launch(void* const* d_in, const int* in_sizes, int n_in,
                              void* d_out, int out_size, void* d_ws, size_t ws_size,
                              hipStream_t stream)
{
    // setup_inputs order: insample, freq, forecast, target, mask
    const float* insample = (const float*)d_in[0];
    const float* forecast = (const float*)d_in[2];
    const float* target   = (const float*)d_in[3];
    const float* mask     = (const float*)d_in[4];
    float* ws  = (float*)d_ws;   // 8192 floats of per-row partials
    float* out = (float*)d_out;

    tildeq_row_kernel<<<NB, 256, 0, stream>>>(insample, forecast, target, mask, ws);
    tildeq_finalize_kernel<<<1, 256, 0, stream>>>(ws, out);
}

// Round 3
// 27.150 us; speedup vs baseline: 1.1619x; 1.1619x over previous
//
#include <hip/hip_runtime.h>
#include <math.h>

// Problem constants (match reference)
constexpr int NB     = 8192;        // batch rows
constexpr int TO     = 720;         // forecast/target length
constexpr int TI     = 1440;        // insample length
constexpr int FRQ    = 24;          // seasonal lag
constexpr int NV4    = TO / 4;      // 180 float4 per row
constexpr int NDIFF  = TI - FRQ;    // 1416 diffs per row
constexpr int NDIFF4 = NDIFF / 4;   // 354 float4 diffs per row
constexpr int WPB    = 4;           // waves per block

__device__ __forceinline__ float wredMax(float v) {
#pragma unroll
    for (int o = 32; o > 0; o >>= 1) v = fmaxf(v, __shfl_xor(v, o, 64));
    return v;
}
__device__ __forceinline__ float wredSum(float v) {
#pragma unroll
    for (int o = 32; o > 0; o >>= 1) v += __shfl_xor(v, o, 64);
    return v;
}

// One WAVE per row: no __syncthreads, no LDS, all reductions are shuffle
// butterflies. Each lane owns 3 float4 slots of the 720-wide row
// (lane, lane+64, lane+128; slot 2 is partial, lanes 0..51 only), so
// dyy stays fully register-resident and f/t/m are read exactly once.
__global__ __launch_bounds__(256) void tildeq_row_kernel(
    const float* __restrict__ insample,
    const float* __restrict__ forecast,
    const float* __restrict__ target,
    const float* __restrict__ mask,
    float* __restrict__ ws)
{
    const int lane = threadIdx.x & 63;
    const int b = blockIdx.x * WPB + (threadIdx.x >> 6);   // row = global wave id

    const float4* f4 = (const float4*)(forecast + (size_t)b * TO);
    const float4* g4 = (const float4*)(target   + (size_t)b * TO);
    const float4* m4 = (const float4*)(mask     + (size_t)b * TO);
    const float4* i4 = (const float4*)(insample + (size_t)b * TI);

    // Slot activity: k=0,1 always; k=2 only lanes with lane+128 < 180.
    const bool act2 = (lane + 128) < NV4;

    float dyy[3][4];
    float pexp[3][4];
    float lmax = -INFINITY, smape_p = 0.f, mase_p = 0.f;

#pragma unroll
    for (int k = 0; k < 3; ++k) {
        const int idx = lane + 64 * k;
        const bool act = (k < 2) || act2;
        if (act) {
            float4 fa = f4[idx], ga = g4[idx], ma = m4[idx];
            float fv[4] = {fa.x, fa.y, fa.z, fa.w};
            float gv[4] = {ga.x, ga.y, ga.z, ga.w};
            float mv[4] = {ma.x, ma.y, ma.z, ma.w};
#pragma unroll
            for (int j = 0; j < 4; ++j) {
                float d  = gv[j] - fv[j];
                float ad = fabsf(d);
                dyy[k][j] = d * mv[j];                    // (target-forecast)*mask
                lmax = fmaxf(lmax, dyy[k][j]);
                mase_p += ad * mv[j];                     // |t-f|*mask
                float den = fabsf(fv[j]) + fabsf(gv[j]);  // detached denom
                float r = (den > 0.f) ? (ad / den) : 0.f; // divide_no_nan
                if (!(r < INFINITY)) r = 0.f;             // kill +inf/NaN
                smape_p += r * mv[j];
            }
        } else {
#pragma unroll
            for (int j = 0; j < 4; ++j) dyy[k][j] = -INFINITY;  // exp -> 0
        }
    }

    // masep: sum |insample[i+24]-insample[i]|, i in [0,1416). +24 = +6 float4,
    // 16B-aligned; the overlapping re-read hits L1/L2.
    float masep_p = 0.f;
    for (int idx = lane; idx < NDIFF4; idx += 64) {
        float4 a = i4[idx];
        float4 c = i4[idx + FRQ / 4];
        masep_p += fabsf(c.x - a.x) + fabsf(c.y - a.y)
                 + fabsf(c.z - a.z) + fabsf(c.w - a.w);
    }

    // Stage 1: row max (6 shuffles).
    const float rmax = wredMax(lmax);

    // exp over register-resident dyy (inactive slots: exp(-inf)=0).
    float sume_p = 0.f;
#pragma unroll
    for (int k = 0; k < 3; ++k)
#pragma unroll
        for (int j = 0; j < 4; ++j) {
            pexp[k][j] = __expf(dyy[k][j] - rmax);
            sume_p += pexp[k][j];
        }

    // Stage 2: fused 4-wide butterfly for the independent sums.
    float s0 = sume_p, s1 = smape_p, s2 = mase_p, s3 = masep_p;
#pragma unroll
    for (int o = 32; o > 0; o >>= 1) {
        s0 += __shfl_xor(s0, o, 64);
        s1 += __shfl_xor(s1, o, 64);
        s2 += __shfl_xor(s2, o, 64);
        s3 += __shfl_xor(s3, o, 64);
    }
    const float sume = s0, smape = s1, mase = s2, msum = s3;

    // Stage 3: eq-sum (needs sume). ONLY active slots contribute the
    // |1/T - p| term — dead slots are not real softmax elements (round-2
    // bug: unguarded dead slots each added 1/720 -> +12.0 on the scalar).
    const float inv_sume = 1.0f / sume;
    float eq_p = 0.f;
#pragma unroll
    for (int k = 0; k < 3; ++k) {
        const bool act = (k < 2) || act2;
        if (act) {
#pragma unroll
            for (int j = 0; j < 4; ++j)
                eq_p += fabsf(1.0f / (float)TO - pexp[k][j] * inv_sume);
        }
    }
    const float eqsum = wredSum(eq_p);

    if (lane == 0) {
        float masep = msum / (float)NDIFF;
        float invm  = (masep == 0.f) ? 0.f : (1.0f / masep);  // divide_no_nan
        if (!(invm < INFINITY)) invm = 0.f;
        float contrib =
            (0.99f * (float)TO / (4.0f * (float)NB)) * eqsum   // mean(loss_TILDEQ)/4
          + (200.0f / ((float)NB * (float)TO)) * smape         // 200*smape
          + (1.0f  / ((float)NB * (float)TO)) * mase * invm;   // MASE term
        ws[b] = contrib;
    }
}

// Deterministic final reduction of the 8192 per-row contributions.
__global__ __launch_bounds__(256) void tildeq_finalize_kernel(
    const float* __restrict__ ws, float* __restrict__ out)
{
    __shared__ float lds[4];
    const int lane = threadIdx.x & 63, w = threadIdx.x >> 6;
    const float4* w4 = (const float4*)ws;
    float s = 0.f;
#pragma unroll
    for (int i = threadIdx.x; i < NB / 4; i += 256) {
        float4 v = w4[i];
        s += (v.x + v.y) + (v.z + v.w);
    }
    s = wredSum(s);
    if (lane == 0) lds[w] = s;
    __syncthreads();
    if (threadIdx.x == 0)
        out[0] = (lds[0] + lds[1]) + (lds[2] + lds[3]);
}

extern "C" void kernel_launch(void* const* d_in, const int* in_sizes, int n_in,
                              void* d_out, int out_size, void* d_ws, size_t ws_size,
                              hipStream_t stream)
{
    // setup_inputs order: insample, freq, forecast, target, mask
    const float* insample = (const float*)d_in[0];
    const float* forecast = (const float*)d_in[2];
    const float* target   = (const float*)d_in[3];
    const float* mask     = (const float*)d_in[4];
    float* ws  = (float*)d_ws;   // 8192 floats of per-row partials
    float* out = (float*)d_out;

    tildeq_row_kernel<<<NB / WPB, 256, 0, stream>>>(insample, forecast, target, mask, ws);
    tildeq_finalize_kernel<<<1, 256, 0, stream>>>(ws, out);
}

// Round 4
// 26.044 us; speedup vs baseline: 1.2113x; 1.0425x over previous
//
#include <hip/hip_runtime.h>
#include <math.h>

// Problem constants (match reference)
constexpr int NB     = 8192;        // batch rows
constexpr int TO     = 720;         // forecast/target length
constexpr int TI     = 1440;        // insample length
constexpr int FRQ    = 24;          // seasonal lag
constexpr int NV4    = TO / 4;      // 180 float4 per row
constexpr int NDIFF  = TI - FRQ;    // 1416 diffs per row
constexpr int NDIFF4 = NDIFF / 4;   // 354 float4 diffs per row
constexpr int WPB    = 4;           // waves per block

__device__ __forceinline__ float wredMax(float v) {
#pragma unroll
    for (int o = 32; o > 0; o >>= 1) v = fmaxf(v, __shfl_xor(v, o, 64));
    return v;
}
__device__ __forceinline__ float wredSum(float v) {
#pragma unroll
    for (int o = 32; o > 0; o >>= 1) v += __shfl_xor(v, o, 64);
    return v;
}

// One WAVE per row, barrier-free, with ALL global loads issued up front so
// ~21 dwordx4 loads are in flight per wave (round-3 version had VGPR=28 ->
// ~2 outstanding loads -> pure latency-bound at 42us). __launch_bounds__
// second arg (min waves/EU) = 4 raises the VGPR cap to 128 so the 84 VGPRs
// of prefetched data stay register-resident.
__global__ __launch_bounds__(256, 4) void tildeq_row_kernel(
    const float* __restrict__ insample,
    const float* __restrict__ forecast,
    const float* __restrict__ target,
    const float* __restrict__ mask,
    float* __restrict__ ws)
{
    const int lane = threadIdx.x & 63;
    const int b = blockIdx.x * WPB + (threadIdx.x >> 6);   // row = global wave id

    const float4* __restrict__ f4 = (const float4*)(forecast + (size_t)b * TO);
    const float4* __restrict__ g4 = (const float4*)(target   + (size_t)b * TO);
    const float4* __restrict__ m4 = (const float4*)(mask     + (size_t)b * TO);
    const float4* __restrict__ i4 = (const float4*)(insample + (size_t)b * TI);

    // Slot 2 of the 180-float4 row covers lanes 0..51 only; tail lanes clamp
    // the index (broadcast load, no branch) and gate their contributions.
    const bool act2 = (lane + 128) < NV4;
    const int  x2   = act2 ? (lane + 128) : (NV4 - 1);
    // insample diff tail: idx5 = lane+320 valid only for lanes < 34.
    const bool act5 = (lane + 320) < NDIFF4;
    const int  x5   = act5 ? (lane + 320) : (NDIFF4 - 1);

    // ---------------- issue ALL loads before any consumption ----------------
    const float4 fa0 = f4[lane      ], ga0 = g4[lane      ], ma0 = m4[lane      ];
    const float4 fa1 = f4[lane +  64], ga1 = g4[lane +  64], ma1 = m4[lane +  64];
    const float4 fa2 = f4[x2        ], ga2 = g4[x2        ], ma2 = m4[x2        ];
    const float4 ia0 = i4[lane      ], ic0 = i4[lane +   6];
    const float4 ia1 = i4[lane +  64], ic1 = i4[lane +  70];
    const float4 ia2 = i4[lane + 128], ic2 = i4[lane + 134];
    const float4 ia3 = i4[lane + 192], ic3 = i4[lane + 198];
    const float4 ia4 = i4[lane + 256], ic4 = i4[lane + 262];
    const float4 ia5 = i4[x5        ], ic5 = i4[x5   +   6];

    // ---------------- consume in issue order ----------------
    float dyy[3][4];
    float lmax = -INFINITY, smape_p = 0.f, mase_p = 0.f;

    auto proc = [&](const float4& fa, const float4& ga, const float4& ma,
                    float* dy) {
        const float fv[4] = {fa.x, fa.y, fa.z, fa.w};
        const float gv[4] = {ga.x, ga.y, ga.z, ga.w};
        const float mv[4] = {ma.x, ma.y, ma.z, ma.w};
#pragma unroll
        for (int j = 0; j < 4; ++j) {
            float d  = gv[j] - fv[j];
            float ad = fabsf(d);
            dy[j] = d * mv[j];                        // (target-forecast)*mask
            lmax = fmaxf(lmax, dy[j]);
            mase_p += ad * mv[j];                     // |t-f|*mask
            float den = fabsf(fv[j]) + fabsf(gv[j]);  // detached denom
            // divide_no_nan: den==0 -> 0; v_rcp handles den=inf -> 0 naturally
            float r = (den > 0.f) ? ad * __builtin_amdgcn_rcpf(den) : 0.f;
            if (!(r < INFINITY)) r = 0.f;             // kill +inf/NaN
            smape_p += r * mv[j];
        }
    };

    proc(fa0, ga0, ma0, dyy[0]);
    proc(fa1, ga1, ma1, dyy[1]);
    if (act2) {
        proc(fa2, ga2, ma2, dyy[2]);
    } else {
#pragma unroll
        for (int j = 0; j < 4; ++j) dyy[2][j] = -INFINITY;  // exp -> 0
    }

    auto d4 = [](const float4& a, const float4& c) {
        return fabsf(c.x - a.x) + fabsf(c.y - a.y)
             + fabsf(c.z - a.z) + fabsf(c.w - a.w);
    };
    float masep_p = d4(ia0, ic0) + d4(ia1, ic1) + d4(ia2, ic2)
                  + d4(ia3, ic3) + d4(ia4, ic4);
    if (act5) masep_p += d4(ia5, ic5);

    // Stage 1: row max (6 shuffles).
    const float rmax = wredMax(lmax);

    // exp over register-resident dyy (inactive slots: exp(-inf)=0).
    float pexp[3][4];
    float sume_p = 0.f;
#pragma unroll
    for (int k = 0; k < 3; ++k)
#pragma unroll
        for (int j = 0; j < 4; ++j) {
            pexp[k][j] = __expf(dyy[k][j] - rmax);
            sume_p += pexp[k][j];
        }

    // Stage 2: fused 4-wide butterfly for the independent sums.
    float s0 = sume_p, s1 = smape_p, s2 = mase_p, s3 = masep_p;
#pragma unroll
    for (int o = 32; o > 0; o >>= 1) {
        s0 += __shfl_xor(s0, o, 64);
        s1 += __shfl_xor(s1, o, 64);
        s2 += __shfl_xor(s2, o, 64);
        s3 += __shfl_xor(s3, o, 64);
    }
    const float sume = s0, smape = s1, mase = s2, msum = s3;

    // Stage 3: eq-sum (needs sume). Only ACTIVE slots contribute |1/T - p|.
    const float inv_sume = 1.0f / sume;
    float eq_p = 0.f;
#pragma unroll
    for (int k = 0; k < 2; ++k)
#pragma unroll
        for (int j = 0; j < 4; ++j)
            eq_p += fabsf(1.0f / (float)TO - pexp[k][j] * inv_sume);
    if (act2) {
#pragma unroll
        for (int j = 0; j < 4; ++j)
            eq_p += fabsf(1.0f / (float)TO - pexp[2][j] * inv_sume);
    }
    const float eqsum = wredSum(eq_p);

    if (lane == 0) {
        float masep = msum / (float)NDIFF;
        float invm  = (masep == 0.f) ? 0.f : (1.0f / masep);  // divide_no_nan
        if (!(invm < INFINITY)) invm = 0.f;
        float contrib =
            (0.99f * (float)TO / (4.0f * (float)NB)) * eqsum   // mean(loss_TILDEQ)/4
          + (200.0f / ((float)NB * (float)TO)) * smape         // 200*smape
          + (1.0f  / ((float)NB * (float)TO)) * mase * invm;   // MASE term
        ws[b] = contrib;
    }
}

// Deterministic final reduction of the 8192 per-row contributions.
__global__ __launch_bounds__(256) void tildeq_finalize_kernel(
    const float* __restrict__ ws, float* __restrict__ out)
{
    __shared__ float lds[4];
    const int lane = threadIdx.x & 63, w = threadIdx.x >> 6;
    const float4* w4 = (const float4*)ws;
    float s = 0.f;
#pragma unroll
    for (int i = threadIdx.x; i < NB / 4; i += 256) {
        float4 v = w4[i];
        s += (v.x + v.y) + (v.z + v.w);
    }
    s = wredSum(s);
    if (lane == 0) lds[w] = s;
    __syncthreads();
    if (threadIdx.x == 0)
        out[0] = (lds[0] + lds[1]) + (lds[2] + lds[3]);
}

extern "C" void kernel_launch(void* const* d_in, const int* in_sizes, int n_in,
                              void* d_out, int out_size, void* d_ws, size_t ws_size,
                              hipStream_t stream)
{
    // setup_inputs order: insample, freq, forecast, target, mask
    const float* insample = (const float*)d_in[0];
    const float* forecast = (const float*)d_in[2];
    const float* target   = (const float*)d_in[3];
    const float* mask     = (const float*)d_in[4];
    float* ws  = (float*)d_ws;   // 8192 floats of per-row partials
    float* out = (float*)d_out;

    tildeq_row_kernel<<<NB / WPB, 256, 0, stream>>>(insample, forecast, target, mask, ws);
    tildeq_finalize_kernel<<<1, 256, 0, stream>>>(ws, out);
}